// Round 16
// baseline (88.972 us; speedup 1.0000x reference)
//
#include <hip/hip_runtime.h>

// ShiftedPatchTokenization on MI355X (gfx950)
// x[64,3,224,224] f32 -> out[64,196,768] f32
// spt_prep (c-split pack || fold_w) -> gb (G/Bt only, 3 blocks) ->
// 224x96 dbuf MFMA GEMM with LN-stats computed in the epilogue from Sp/Qp.

typedef short bf16x8 __attribute__((ext_vector_type(8)));
typedef unsigned short u16x8 __attribute__((ext_vector_type(8)));
typedef float f32x4 __attribute__((ext_vector_type(4)));

#define GLOBAL_AS __attribute__((address_space(1)))
#define LDS_AS __attribute__((address_space(3)))

__device__ __forceinline__ unsigned short f2bf(float f) {
  union { float f; unsigned int u; } v;
  v.f = f;
  unsigned int u = v.u;
  unsigned int r = (u + 0x7FFFu + ((u >> 16) & 1u)) >> 16;  // RNE
  return (unsigned short)r;
}

// ---------------------------------------------------------------------------
// Kernel 1: FUSED prep (r14 best-measured version), grid 2904 x 512.
// Per XCD chunk of 363: local<336 -> PACK unit (one (b,hi,c), 2-iter chain,
// ~36 KB LDS); local>=336 -> FOLD unit (2x256-thread halves).
// Pack writes V segments + per-(token,c) stats partials Sp/Qp.
// ---------------------------------------------------------------------------
__global__ __launch_bounds__(512, 6) void spt_prep(
    const float* __restrict__ x, const float* __restrict__ gamma,
    const float* __restrict__ beta, const float* __restrict__ w,
    unsigned short* __restrict__ V, float* __restrict__ Sp,
    float* __restrict__ Qp, unsigned short* __restrict__ w2t,
    float* __restrict__ Gp, float* __restrict__ Bp)
{
  __shared__ __align__(16) char smem[36064];  // max(pack 36064, fold 32896)
  const int t = threadIdx.x;
  const int xcd = blockIdx.x & 7;
  const int local = blockIdx.x >> 3;  // 0..362

  if (local < 336) {
    // ------------------------- PACK (one channel) -------------------------
    unsigned short* slab = (unsigned short*)smem;   // [14][776]: 3 segs of 256 + pad
    float* sred = (float*)(smem + 21728);           // [8][224]
    float* qred = sred + 1792;
    const int bi = xcd * 336 + local;               // (b*14+hi)*3 + c
    const int th = bi / 3, c = bi % 3;
    const int b = th / 14, hi = th % 14;
    const float TW = 16.0f / 224.0f;

    const int q = t % 56;
    const int grp = t / 56;     // 0..9; active grp<8
    const int x4 = q * 4;

    int sloff[4];
    {
      int wi = x4 % 14, p2 = x4 / 14;
      #pragma unroll
      for (int j = 0; j < 4; ++j) {
        sloff[j] = wi * 776 + p2;
        if (++wi == 14) { wi = 0; ++p2; }
      }
    }

    if (grp < 8) {
      f32x4 sAcc = {0.f, 0.f, 0.f, 0.f}, qAcc = {0.f, 0.f, 0.f, 0.f};
      #pragma unroll
      for (int it = 0; it < 2; ++it) {
        const int p1 = grp * 2 + it;
        const int y = p1 * 14 + hi;
        const float* row = x + ((size_t)(b * 3 + c)) * 50176 + (size_t)y * 224;
        const f32x4 xv = *(const f32x4*)(row + x4);
        f32x4 ra = {0.f,0.f,0.f,0.f}, rb = {0.f,0.f,0.f,0.f};
        f32x4 la = {0.f,0.f,0.f,0.f}, lb = {0.f,0.f,0.f,0.f};
        if (q < 54) {
          ra = *(const f32x4*)(row + x4 + 8);
          if (y < 223) rb = *(const f32x4*)(row + x4 + 8 + 224);
        }
        if (q >= 2) {
          la = *(const f32x4*)(row + x4 - 8);
          if (y > 0) lb = *(const f32x4*)(row + x4 - 8 - 224);
        }
        const f32x4 rv = (1.0f - TW) * ra + TW * rb;
        const f32x4 lv = (1.0f - TW) * la + TW * lb;
        sAcc += xv + 2.0f * (lv + rv);
        qAcc += xv * xv + 2.0f * (lv * lv + rv * rv);
        const int kb = p1 * 16;
        #pragma unroll
        for (int j = 0; j < 4; ++j) {
          slab[sloff[j] + kb]        = f2bf(xv[j]);   // seg 0: x
          slab[sloff[j] + kb + 256]  = f2bf(lv[j]);   // seg 1: left
          slab[sloff[j] + kb + 512]  = f2bf(rv[j]);   // seg 2: right
        }
      }
      #pragma unroll
      for (int j = 0; j < 4; ++j) {
        sred[grp * 224 + x4 + j] = sAcc[j];
        qred[grp * 224 + x4 + j] = qAcc[j];
      }
    }
    __syncthreads();

    if (t < 224) {
      float ss = 0.f, qq = 0.f;
      #pragma unroll
      for (int g = 0; g < 8; ++g) { ss += sred[g * 224 + t]; qq += qred[g * 224 + t]; }
      sred[t] = ss;  // column-private
      qred[t] = qq;
    }
    __syncthreads();

    const int tok0 = b * 196 + hi * 14;
    if (t < 14) {
      float S = 0.f, Q = 0.f;
      #pragma unroll
      for (int p = 0; p < 16; ++p) { S += sred[t + 14 * p]; Q += qred[t + 14 * p]; }
      Sp[c * 12544 + tok0 + t] = S;
      Qp[c * 12544 + tok0 + t] = Q;
    }

    // copy-out: 14 tokens x 3 segs x 32 16B-chunks = 1344 chunks
    for (int i = t; i < 1344; i += 512) {
      const int wi2 = i / 96, s = i % 96;
      const int g = s >> 5, i8 = s & 31;
      *(u16x8*)&V[(size_t)(tok0 + wi2) * 2304 + g * 768 + c * 256 + i8 * 8] =
          *(const u16x8*)&slab[wi2 * 776 + g * 256 + i8 * 8];
    }
  } else {
    // ------------------------- FOLD_W -------------------------
    float* tileF = (float*)smem;                    // [32][257]
    const int fu = xcd * 27 + (local - 336);        // 0..215
    const int fx = fu / 3;                          // 0..71
    const int fy = fu % 3;
    const int half = t >> 8;                        // 2 independent halves
    const int tt = t & 255;
    const int j = fy * 256 + tt;
    const int f2blk = fx * 32 + half * 16;

    float gacc = 0.f, bacc = 0.f;
    #pragma unroll
    for (int i = 0; i < 16; ++i) {
      const int f2 = f2blk + i;
      const int g = f2 / 768;
      const int rem = f2 % 768;  // c*256 + p1*16 + p2
      float v, bv;
      if (g == 0) {
        const int f = rem;
        const float wv = w[(size_t)f * 768 + j];
        v = gamma[f] * wv;
        bv = beta[f] * wv;
      } else if (g == 1) {
        const int fa = 768 + rem, fb = 2304 + rem;   // left_up, left_down
        const float wa = w[(size_t)fa * 768 + j], wb = w[(size_t)fb * 768 + j];
        v = gamma[fa] * wa + gamma[fb] * wb;
        bv = beta[fa] * wa + beta[fb] * wb;
      } else {
        const int fa = 1536 + rem, fb = 3072 + rem;  // right_up, right_down
        const float wa = w[(size_t)fa * 768 + j], wb = w[(size_t)fb * 768 + j];
        v = gamma[fa] * wa + gamma[fb] * wb;
        bv = beta[fa] * wa + beta[fb] * wb;
      }
      tileF[(half * 16 + i) * 257 + tt] = v;
      gacc += v;
      bacc += bv;
    }
    __syncthreads();
    u16x8 lo, hi;
    #pragma unroll
    for (int i = 0; i < 8; ++i) {
      lo[i] = f2bf(tileF[(half * 16 + i) * 257 + tt]);
      hi[i] = f2bf(tileF[(half * 16 + 8 + i) * 257 + tt]);
    }
    unsigned short* dst = w2t + (size_t)j * 2304 + f2blk;
    *(u16x8*)dst = lo;
    *(u16x8*)(dst + 8) = hi;
    Gp[(fx * 2 + half) * 768 + j] = gacc;
    Bp[(fx * 2 + half) * 768 + j] = bacc;
  }
}

// ---------------------------------------------------------------------------
// Kernel 2: reduce 144 partials -> G[768], Bt[768] (+b). grid 3, block 256
// (stats finish moved into the GEMM epilogue)
// ---------------------------------------------------------------------------
__global__ __launch_bounds__(256) void spt_gb(
    const float* __restrict__ Gp, const float* __restrict__ Bp,
    const float* __restrict__ bvec, float* __restrict__ G, float* __restrict__ Bt)
{
  const int j = blockIdx.x * 256 + threadIdx.x;
  float g = 0.f, bb = 0.f;
  for (int i = 0; i < 144; ++i) {
    g += Gp[i * 768 + j];
    bb += Bp[i * 768 + j];
  }
  G[j] = g;
  Bt[j] = bb + bvec[j];
}

// ---------------------------------------------------------------------------
// Kernel 3: GEMM  out[m][j] = r_m * (V[m,:] . w2t[j,:]) + (-mu*r)_m * G[j] + Bt[j]
// Best measured variant: 224x96 tile, BK=64, 4 waves (2x2, wave 112x48),
// dbuf 80 KiB -> 2 blocks/CU, counted vmcnt(10), raw s_barrier, XOR swizzle
// w/ pre-swizzled source, hoisted frags + setprio. Epilogue computes LN stats
// from the 3 per-channel partials (Sp/Qp) directly.
// grid 448 = 56m x 8n, exact XCD swizzle, N-fastest.
// ---------------------------------------------------------------------------
__global__ __launch_bounds__(256, 2) void spt_gemm(
    const unsigned short* __restrict__ V, const unsigned short* __restrict__ w2t,
    const float* __restrict__ Sp, const float* __restrict__ Qp,
    const float* __restrict__ G, const float* __restrict__ Bt,
    float* __restrict__ out)
{
  __shared__ unsigned short Alds[2][224 * 64];
  __shared__ unsigned short Blds[2][96 * 64];

  const int orig = blockIdx.x;
  const int wgid = (orig & 7) * 56 + (orig >> 3);  // exact: 448 = 8 * 56
  const int m0 = (wgid >> 3) * 224;
  const int n0 = (wgid & 7) * 96;
  const int t = threadIdx.x;
  const int w = t >> 6, l = t & 63;
  const int wr = w >> 1;   // 0..1 -> 112-row half
  const int wn = w & 1;    // 0..1 -> 48-col slice

  f32x4 acc[7][3] = {};

#define STAGE(pb, kt)                                                          \
  {                                                                            \
    const int k0s = (kt) << 6;                                                 \
    _Pragma("unroll") for (int i = 0; i < 7; ++i) {                            \
      const int c = i * 256 + t;                                               \
      const int row = c >> 3;                                                  \
      const int srcel = (((c & 7) ^ (row & 7)) << 3);                          \
      const unsigned short* ga = V + (size_t)(m0 + row) * 2304 + k0s + srcel;  \
      __builtin_amdgcn_global_load_lds((const GLOBAL_AS unsigned int*)ga,      \
          (LDS_AS unsigned int*)&Alds[pb][i * 2048 + w * 512], 16, 0, 0);      \
    }                                                                          \
    _Pragma("unroll") for (int i = 0; i < 3; ++i) {                            \
      const int c = i * 256 + t;                                               \
      const int row = c >> 3;                                                  \
      const int srcel = (((c & 7) ^ (row & 7)) << 3);                          \
      const unsigned short* gb = w2t + (size_t)(n0 + row) * 2304 + k0s + srcel;\
      __builtin_amdgcn_global_load_lds((const GLOBAL_AS unsigned int*)gb,      \
          (LDS_AS unsigned int*)&Blds[pb][i * 2048 + w * 512], 16, 0, 0);      \
    }                                                                          \
  }

#define COMPUTE(pb)                                                            \
  {                                                                            \
    const int lane15 = l & 15;                                                 \
    const int kcol = (l >> 4) << 4;                                            \
    bf16x8 bF[2][3], aF[2][7];                                                 \
    _Pragma("unroll") for (int kk = 0; kk < 2; ++kk) {                         \
      const int kb = kk * 64 + kcol;                                           \
      _Pragma("unroll") for (int n = 0; n < 3; ++n) {                          \
        const int row = wn * 48 + n * 16 + lane15;                             \
        const int phys = row * 128 + (kb ^ ((row & 7) << 4));                  \
        bF[kk][n] = *(const bf16x8*)&Blds[pb][phys >> 1];                      \
      }                                                                        \
      _Pragma("unroll") for (int m = 0; m < 7; ++m) {                          \
        const int row = wr * 112 + m * 16 + lane15;                            \
        const int phys = row * 128 + (kb ^ ((row & 7) << 4));                  \
        aF[kk][m] = *(const bf16x8*)&Alds[pb][phys >> 1];                      \
      }                                                                        \
    }                                                                          \
    __builtin_amdgcn_s_setprio(1);                                             \
    _Pragma("unroll") for (int kk = 0; kk < 2; ++kk)                           \
      _Pragma("unroll") for (int m = 0; m < 7; ++m)                            \
        _Pragma("unroll") for (int n = 0; n < 3; ++n)                          \
          acc[m][n] = __builtin_amdgcn_mfma_f32_16x16x32_bf16(aF[kk][m],       \
                          bF[kk][n], acc[m][n], 0, 0, 0);                      \
    __builtin_amdgcn_s_setprio(0);                                             \
  }

  STAGE(0, 0);
  int pb = 0;
  for (int kt = 0; kt < 35; ++kt) {
    STAGE(pb ^ 1, kt + 1);
    // wait for the 10 oldest loads (step kt); 10 newest (kt+1) stay in flight
    asm volatile("s_waitcnt vmcnt(10)\n\ts_barrier" ::: "memory");
    COMPUTE(pb);
    asm volatile("s_barrier" ::: "memory");  // reads of buf pb done before restage
    pb ^= 1;
  }
  asm volatile("s_waitcnt vmcnt(0)\n\ts_barrier" ::: "memory");
  COMPUTE(pb);

  // Epilogue: C/D frag layout col = l&15, row = (l>>4)*4 + reg.
  // LN stats computed inline from channel partials.
  const int lane15 = l & 15;
  const int lg = (l >> 4) * 4;
  #pragma unroll
  for (int m = 0; m < 7; ++m) {
    const int rowb = m0 + wr * 112 + m * 16 + lg;
    float2 st[4];
    #pragma unroll
    for (int r = 0; r < 4; ++r) {
      const int tok = rowb + r;
      const float S = Sp[tok] + Sp[12544 + tok] + Sp[25088 + tok];
      const float Q = Qp[tok] + Qp[12544 + tok] + Qp[25088 + tok];
      const float mu = S / 3840.f;
      const float var = Q / 3840.f - mu * mu;
      const float rr = rsqrtf(var + 1e-5f);
      st[r] = make_float2(rr, -mu * rr);
    }
    #pragma unroll
    for (int n = 0; n < 3; ++n) {
      const int col = n0 + wn * 48 + n * 16 + lane15;
      const float Gc = G[col];
      const float Bc = Bt[col];
      #pragma unroll
      for (int r = 0; r < 4; ++r) {
        out[(size_t)(rowb + r) * 768 + col] = st[r].x * acc[m][n][r] + st[r].y * Gc + Bc;
      }
    }
  }
#undef STAGE
#undef COMPUTE
}

// ---------------------------------------------------------------------------
// Workspace layout (bytes):
//   V     : 0            57,802,752
//   w2t   : 57,802,752    3,538,944
//   (gap) : 61,341,696      100,352   (unused; was stats)
//   G     : 61,442,048        3,072
//   Bt    : 61,445,120        3,072
//   Gp    : 61,448,192      442,368
//   Bp    : 61,890,560      442,368
//   Sp    : 62,332,928      150,528
//   Qp    : 62,483,456      150,528   -> total 62,633,984
// ---------------------------------------------------------------------------
extern "C" void kernel_launch(void* const* d_in, const int* in_sizes, int n_in,
                              void* d_out, int out_size, void* d_ws, size_t ws_size,
                              hipStream_t stream) {
  const float* x     = (const float*)d_in[0];
  const float* gamma = (const float*)d_in[1];
  const float* beta  = (const float*)d_in[2];
  const float* w     = (const float*)d_in[3];
  const float* bvec  = (const float*)d_in[4];
  float* out = (float*)d_out;

  char* ws = (char*)d_ws;
  unsigned short* V   = (unsigned short*)(ws);
  unsigned short* w2t = (unsigned short*)(ws + 57802752);
  float* G            = (float*)(ws + 61442048);
  float* Bt           = (float*)(ws + 61445120);
  float* Gp           = (float*)(ws + 61448192);
  float* Bp           = (float*)(ws + 61890560);
  float* Sp           = (float*)(ws + 62332928);
  float* Qp           = (float*)(ws + 62483456);

  spt_prep<<<2904, 512, 0, stream>>>(x, gamma, beta, w, V, Sp, Qp, w2t, Gp, Bp);
  spt_gb<<<3, 256, 0, stream>>>(Gp, Bp, bvec, G, Bt);
  spt_gemm<<<448, 256, 0, stream>>>(V, w2t, Sp, Qp, G, Bt, out);
}

// Round 17
// 85.953 us; speedup vs baseline: 1.0351x; 1.0351x over previous
//
#include <hip/hip_runtime.h>

// ShiftedPatchTokenization on MI355X (gfx950)
// x[64,3,224,224] f32 -> out[64,196,768] f32
// BEST-MEASURED CONFIG (round 14, 86.2 us):
// spt_prep (c-split pack || fold_w, one launch) -> gb (+stats finish) ->
// 224x96 dbuf MFMA GEMM.

typedef short bf16x8 __attribute__((ext_vector_type(8)));
typedef unsigned short u16x8 __attribute__((ext_vector_type(8)));
typedef float f32x4 __attribute__((ext_vector_type(4)));

#define GLOBAL_AS __attribute__((address_space(1)))
#define LDS_AS __attribute__((address_space(3)))

__device__ __forceinline__ unsigned short f2bf(float f) {
  union { float f; unsigned int u; } v;
  v.f = f;
  unsigned int u = v.u;
  unsigned int r = (u + 0x7FFFu + ((u >> 16) & 1u)) >> 16;  // RNE
  return (unsigned short)r;
}

// ---------------------------------------------------------------------------
// Kernel 1: FUSED prep, grid 2904 x 512.
// Per XCD chunk of 363: local<336 -> PACK unit (c-split: one (b,hi,c) per
// block, 2-iter latency chain, ~36 KB LDS); local>=336 -> FOLD unit
// (2x256-thread halves, 32 k-rows of gamma*w fold).
// Pack writes V segments + per-(token,c) stats partials Sp/Qp.
// ---------------------------------------------------------------------------
__global__ __launch_bounds__(512, 6) void spt_prep(
    const float* __restrict__ x, const float* __restrict__ gamma,
    const float* __restrict__ beta, const float* __restrict__ w,
    unsigned short* __restrict__ V, float* __restrict__ Sp,
    float* __restrict__ Qp, unsigned short* __restrict__ w2t,
    float* __restrict__ Gp, float* __restrict__ Bp)
{
  __shared__ __align__(16) char smem[36064];  // max(pack 36064, fold 32896)
  const int t = threadIdx.x;
  const int xcd = blockIdx.x & 7;
  const int local = blockIdx.x >> 3;  // 0..362

  if (local < 336) {
    // ------------------------- PACK (one channel) -------------------------
    unsigned short* slab = (unsigned short*)smem;   // [14][776]: 3 segs of 256 + pad
    float* sred = (float*)(smem + 21728);           // [8][224]
    float* qred = sred + 1792;
    const int bi = xcd * 336 + local;               // (b*14+hi)*3 + c
    const int th = bi / 3, c = bi % 3;
    const int b = th / 14, hi = th % 14;
    const float TW = 16.0f / 224.0f;

    const int q = t % 56;
    const int grp = t / 56;     // 0..9; active grp<8
    const int x4 = q * 4;

    int sloff[4];
    {
      int wi = x4 % 14, p2 = x4 / 14;
      #pragma unroll
      for (int j = 0; j < 4; ++j) {
        sloff[j] = wi * 776 + p2;
        if (++wi == 14) { wi = 0; ++p2; }
      }
    }

    if (grp < 8) {
      f32x4 sAcc = {0.f, 0.f, 0.f, 0.f}, qAcc = {0.f, 0.f, 0.f, 0.f};
      #pragma unroll
      for (int it = 0; it < 2; ++it) {
        const int p1 = grp * 2 + it;
        const int y = p1 * 14 + hi;
        const float* row = x + ((size_t)(b * 3 + c)) * 50176 + (size_t)y * 224;
        const f32x4 xv = *(const f32x4*)(row + x4);
        f32x4 ra = {0.f,0.f,0.f,0.f}, rb = {0.f,0.f,0.f,0.f};
        f32x4 la = {0.f,0.f,0.f,0.f}, lb = {0.f,0.f,0.f,0.f};
        if (q < 54) {
          ra = *(const f32x4*)(row + x4 + 8);
          if (y < 223) rb = *(const f32x4*)(row + x4 + 8 + 224);
        }
        if (q >= 2) {
          la = *(const f32x4*)(row + x4 - 8);
          if (y > 0) lb = *(const f32x4*)(row + x4 - 8 - 224);
        }
        const f32x4 rv = (1.0f - TW) * ra + TW * rb;
        const f32x4 lv = (1.0f - TW) * la + TW * lb;
        sAcc += xv + 2.0f * (lv + rv);
        qAcc += xv * xv + 2.0f * (lv * lv + rv * rv);
        const int kb = p1 * 16;
        #pragma unroll
        for (int j = 0; j < 4; ++j) {
          slab[sloff[j] + kb]        = f2bf(xv[j]);   // seg 0: x
          slab[sloff[j] + kb + 256]  = f2bf(lv[j]);   // seg 1: left
          slab[sloff[j] + kb + 512]  = f2bf(rv[j]);   // seg 2: right
        }
      }
      #pragma unroll
      for (int j = 0; j < 4; ++j) {
        sred[grp * 224 + x4 + j] = sAcc[j];
        qred[grp * 224 + x4 + j] = qAcc[j];
      }
    }
    __syncthreads();

    if (t < 224) {
      float ss = 0.f, qq = 0.f;
      #pragma unroll
      for (int g = 0; g < 8; ++g) { ss += sred[g * 224 + t]; qq += qred[g * 224 + t]; }
      sred[t] = ss;  // column-private
      qred[t] = qq;
    }
    __syncthreads();

    const int tok0 = b * 196 + hi * 14;
    if (t < 14) {
      float S = 0.f, Q = 0.f;
      #pragma unroll
      for (int p = 0; p < 16; ++p) { S += sred[t + 14 * p]; Q += qred[t + 14 * p]; }
      Sp[c * 12544 + tok0 + t] = S;
      Qp[c * 12544 + tok0 + t] = Q;
    }

    // copy-out: 14 tokens x 3 segs x 32 16B-chunks = 1344 chunks
    for (int i = t; i < 1344; i += 512) {
      const int wi2 = i / 96, s = i % 96;
      const int g = s >> 5, i8 = s & 31;
      *(u16x8*)&V[(size_t)(tok0 + wi2) * 2304 + g * 768 + c * 256 + i8 * 8] =
          *(const u16x8*)&slab[wi2 * 776 + g * 256 + i8 * 8];
    }
  } else {
    // ------------------------- FOLD_W -------------------------
    float* tileF = (float*)smem;                    // [32][257]
    const int fu = xcd * 27 + (local - 336);        // 0..215
    const int fx = fu / 3;                          // 0..71
    const int fy = fu % 3;
    const int half = t >> 8;                        // 2 independent halves
    const int tt = t & 255;
    const int j = fy * 256 + tt;
    const int f2blk = fx * 32 + half * 16;

    float gacc = 0.f, bacc = 0.f;
    #pragma unroll
    for (int i = 0; i < 16; ++i) {
      const int f2 = f2blk + i;
      const int g = f2 / 768;
      const int rem = f2 % 768;  // c*256 + p1*16 + p2
      float v, bv;
      if (g == 0) {
        const int f = rem;
        const float wv = w[(size_t)f * 768 + j];
        v = gamma[f] * wv;
        bv = beta[f] * wv;
      } else if (g == 1) {
        const int fa = 768 + rem, fb = 2304 + rem;   // left_up, left_down
        const float wa = w[(size_t)fa * 768 + j], wb = w[(size_t)fb * 768 + j];
        v = gamma[fa] * wa + gamma[fb] * wb;
        bv = beta[fa] * wa + beta[fb] * wb;
      } else {
        const int fa = 1536 + rem, fb = 3072 + rem;  // right_up, right_down
        const float wa = w[(size_t)fa * 768 + j], wb = w[(size_t)fb * 768 + j];
        v = gamma[fa] * wa + gamma[fb] * wb;
        bv = beta[fa] * wa + beta[fb] * wb;
      }
      tileF[(half * 16 + i) * 257 + tt] = v;
      gacc += v;
      bacc += bv;
    }
    __syncthreads();
    u16x8 lo, hi;
    #pragma unroll
    for (int i = 0; i < 8; ++i) {
      lo[i] = f2bf(tileF[(half * 16 + i) * 257 + tt]);
      hi[i] = f2bf(tileF[(half * 16 + 8 + i) * 257 + tt]);
    }
    unsigned short* dst = w2t + (size_t)j * 2304 + f2blk;
    *(u16x8*)dst = lo;
    *(u16x8*)(dst + 8) = hi;
    Gp[(fx * 2 + half) * 768 + j] = gacc;
    Bp[(fx * 2 + half) * 768 + j] = bacc;
  }
}

// ---------------------------------------------------------------------------
// Kernel 2: blocks 0-2: reduce 144 partials -> G[768], Bt[768] (+b).
// blocks 3-51: finish LN stats (sum 3 channel partials, 256 tokens each).
// grid 52, block 256
// ---------------------------------------------------------------------------
__global__ __launch_bounds__(256) void spt_gb(
    const float* __restrict__ Gp, const float* __restrict__ Bp,
    const float* __restrict__ bvec, const float* __restrict__ Sp,
    const float* __restrict__ Qp, float* __restrict__ G,
    float* __restrict__ Bt, float2* __restrict__ stats)
{
  const int t = threadIdx.x;
  if (blockIdx.x < 3) {
    const int j = blockIdx.x * 256 + t;
    float g = 0.f, bb = 0.f;
    for (int i = 0; i < 144; ++i) {
      g += Gp[i * 768 + j];
      bb += Bp[i * 768 + j];
    }
    G[j] = g;
    Bt[j] = bb + bvec[j];
  } else {
    const int tok = (blockIdx.x - 3) * 256 + t;  // 49*256 = 12544
    const float S = Sp[tok] + Sp[12544 + tok] + Sp[25088 + tok];
    const float Q = Qp[tok] + Qp[12544 + tok] + Qp[25088 + tok];
    const float mu = S / 3840.f;
    const float var = Q / 3840.f - mu * mu;
    const float r = rsqrtf(var + 1e-5f);
    stats[tok] = make_float2(r, -mu * r);
  }
}

// ---------------------------------------------------------------------------
// Kernel 3: GEMM  out[m][j] = r_m * (V[m,:] . w2t[j,:]) + (-mu*r)_m * G[j] + Bt[j]
// Best measured variant: 224x96 tile, BK=64, 4 waves (2x2, wave 112x48),
// dbuf 80 KiB -> 2 blocks/CU, counted vmcnt(10), raw s_barrier, XOR swizzle
// w/ pre-swizzled source, hoisted frags + setprio.
// grid 448 = 56m x 8n, exact XCD swizzle, N-fastest.
// ---------------------------------------------------------------------------
__global__ __launch_bounds__(256, 2) void spt_gemm(
    const unsigned short* __restrict__ V, const unsigned short* __restrict__ w2t,
    const float2* __restrict__ stats, const float* __restrict__ G,
    const float* __restrict__ Bt, float* __restrict__ out)
{
  __shared__ unsigned short Alds[2][224 * 64];
  __shared__ unsigned short Blds[2][96 * 64];

  const int orig = blockIdx.x;
  const int wgid = (orig & 7) * 56 + (orig >> 3);  // exact: 448 = 8 * 56
  const int m0 = (wgid >> 3) * 224;
  const int n0 = (wgid & 7) * 96;
  const int t = threadIdx.x;
  const int w = t >> 6, l = t & 63;
  const int wr = w >> 1;   // 0..1 -> 112-row half
  const int wn = w & 1;    // 0..1 -> 48-col slice

  f32x4 acc[7][3] = {};

#define STAGE(pb, kt)                                                          \
  {                                                                            \
    const int k0s = (kt) << 6;                                                 \
    _Pragma("unroll") for (int i = 0; i < 7; ++i) {                            \
      const int c = i * 256 + t;                                               \
      const int row = c >> 3;                                                  \
      const int srcel = (((c & 7) ^ (row & 7)) << 3);                          \
      const unsigned short* ga = V + (size_t)(m0 + row) * 2304 + k0s + srcel;  \
      __builtin_amdgcn_global_load_lds((const GLOBAL_AS unsigned int*)ga,      \
          (LDS_AS unsigned int*)&Alds[pb][i * 2048 + w * 512], 16, 0, 0);      \
    }                                                                          \
    _Pragma("unroll") for (int i = 0; i < 3; ++i) {                            \
      const int c = i * 256 + t;                                               \
      const int row = c >> 3;                                                  \
      const int srcel = (((c & 7) ^ (row & 7)) << 3);                          \
      const unsigned short* gb = w2t + (size_t)(n0 + row) * 2304 + k0s + srcel;\
      __builtin_amdgcn_global_load_lds((const GLOBAL_AS unsigned int*)gb,      \
          (LDS_AS unsigned int*)&Blds[pb][i * 2048 + w * 512], 16, 0, 0);      \
    }                                                                          \
  }

#define COMPUTE(pb)                                                            \
  {                                                                            \
    const int lane15 = l & 15;                                                 \
    const int kcol = (l >> 4) << 4;                                            \
    bf16x8 bF[2][3], aF[2][7];                                                 \
    _Pragma("unroll") for (int kk = 0; kk < 2; ++kk) {                         \
      const int kb = kk * 64 + kcol;                                           \
      _Pragma("unroll") for (int n = 0; n < 3; ++n) {                          \
        const int row = wn * 48 + n * 16 + lane15;                             \
        const int phys = row * 128 + (kb ^ ((row & 7) << 4));                  \
        bF[kk][n] = *(const bf16x8*)&Blds[pb][phys >> 1];                      \
      }                                                                        \
      _Pragma("unroll") for (int m = 0; m < 7; ++m) {                          \
        const int row = wr * 112 + m * 16 + lane15;                            \
        const int phys = row * 128 + (kb ^ ((row & 7) << 4));                  \
        aF[kk][m] = *(const bf16x8*)&Alds[pb][phys >> 1];                      \
      }                                                                        \
    }                                                                          \
    __builtin_amdgcn_s_setprio(1);                                             \
    _Pragma("unroll") for (int kk = 0; kk < 2; ++kk)                           \
      _Pragma("unroll") for (int m = 0; m < 7; ++m)                            \
        _Pragma("unroll") for (int n = 0; n < 3; ++n)                          \
          acc[m][n] = __builtin_amdgcn_mfma_f32_16x16x32_bf16(aF[kk][m],       \
                          bF[kk][n], acc[m][n], 0, 0, 0);                      \
    __builtin_amdgcn_s_setprio(0);                                             \
  }

  STAGE(0, 0);
  int pb = 0;
  for (int kt = 0; kt < 35; ++kt) {
    STAGE(pb ^ 1, kt + 1);
    // wait for the 10 oldest loads (step kt); 10 newest (kt+1) stay in flight
    asm volatile("s_waitcnt vmcnt(10)\n\ts_barrier" ::: "memory");
    COMPUTE(pb);
    asm volatile("s_barrier" ::: "memory");  // reads of buf pb done before restage
    pb ^= 1;
  }
  asm volatile("s_waitcnt vmcnt(0)\n\ts_barrier" ::: "memory");
  COMPUTE(pb);

  // Epilogue: C/D frag layout col = l&15, row = (l>>4)*4 + reg
  const int lane15 = l & 15;
  const int lg = (l >> 4) * 4;
  #pragma unroll
  for (int m = 0; m < 7; ++m) {
    const int rowb = m0 + wr * 112 + m * 16 + lg;
    float2 st[4];
    #pragma unroll
    for (int r = 0; r < 4; ++r) st[r] = stats[rowb + r];
    #pragma unroll
    for (int n = 0; n < 3; ++n) {
      const int col = n0 + wn * 48 + n * 16 + lane15;
      const float Gc = G[col];
      const float Bc = Bt[col];
      #pragma unroll
      for (int r = 0; r < 4; ++r) {
        out[(size_t)(rowb + r) * 768 + col] = st[r].x * acc[m][n][r] + st[r].y * Gc + Bc;
      }
    }
  }
#undef STAGE
#undef COMPUTE
}

// ---------------------------------------------------------------------------
// Workspace layout (bytes):
//   V     : 0            57,802,752
//   w2t   : 57,802,752    3,538,944
//   stats : 61,341,696      100,352
//   G     : 61,442,048        3,072
//   Bt    : 61,445,120        3,072
//   Gp    : 61,448,192      442,368
//   Bp    : 61,890,560      442,368
//   Sp    : 62,332,928      150,528
//   Qp    : 62,483,456      150,528   -> total 62,633,984
// ---------------------------------------------------------------------------
extern "C" void kernel_launch(void* const* d_in, const int* in_sizes, int n_in,
                              void* d_out, int out_size, void* d_ws, size_t ws_size,
                              hipStream_t stream) {
  const float* x     = (const float*)d_in[0];
  const float* gamma = (const float*)d_in[1];
  const float* beta  = (const float*)d_in[2];
  const float* w     = (const float*)d_in[3];
  const float* bvec  = (const float*)d_in[4];
  float* out = (float*)d_out;

  char* ws = (char*)d_ws;
  unsigned short* V   = (unsigned short*)(ws);
  unsigned short* w2t = (unsigned short*)(ws + 57802752);
  float2* stats       = (float2*)(ws + 61341696);
  float* G            = (float*)(ws + 61442048);
  float* Bt           = (float*)(ws + 61445120);
  float* Gp           = (float*)(ws + 61448192);
  float* Bp           = (float*)(ws + 61890560);
  float* Sp           = (float*)(ws + 62332928);
  float* Qp           = (float*)(ws + 62483456);

  spt_prep<<<2904, 512, 0, stream>>>(x, gamma, beta, w, V, Sp, Qp, w2t, Gp, Bp);
  spt_gb<<<52, 256, 0, stream>>>(Gp, Bp, bvec, Sp, Qp, G, Bt, stats);
  spt_gemm<<<448, 256, 0, stream>>>(V, w2t, stats, G, Bt, out);
}